// Round 5
// baseline (482.508 us; speedup 1.0000x reference)
//
#include <hip/hip_runtime.h>

// LightGCN 3-layer propagation. out layout: [4, N_NODES, DIM] f32.
//   layer 0 = embeddings (copy); layer l = SpMM(layer l-1).
//
// Build-stage ledger:
//  R4: node-scatter + dst-range(blockIdx%8): WRITE 77.5->73 MB. No merge.
//  R5: bucket streams: 755us. >700 returning atomics/addr serialize at the
//      coherence point (~410ns each). Rule: per-addr multiplicity <= tens.
//  R6: +NT edge loads: WRITE 73->54.6, dur 64us. Best scatter so far.
//  R7: physical-XCD binding (s_getreg XCC_ID): WRITE UNCHANGED (54.2).
//      -> partial-line write-amp is STRUCTURAL (sector writeback), not a
//      cache-affinity problem. Ranges only cost replicated reads. Ticket
//      loop added imbalance (+10us).
//  R8 (this round):
//    - scatter: single-pass, no ranges (kill 8x read replication), NT loads,
//      cur pre-seeded with off (one atomic, no off gather).
//    - spmm: hex scheme (16 edges in flight, 4 lanes x 4 float4 per edge) +
//      wave-preloaded pairs broadcast via __shfl (no dependent pairs load in
//      the loop). deg~12 -> ONE gather round per node.

#define N_NODES 100000
#define DIM 64
#define SCAN_CHUNK 1024   // elements scanned per block in scan1 (256 thr x 4)

typedef int   vint4   __attribute__((ext_vector_type(4)));
typedef float vfloat4 __attribute__((ext_vector_type(4)));

// ---------------- CSR build ----------------

// Single-pass vectorized histogram. Atomics resolve at the memory-side
// coherence point; ~12 per address -> uncontended.
__global__ void hist_kernel(const int* __restrict__ edst, int* __restrict__ deg, int E) {
    int i = blockIdx.x * blockDim.x + threadIdx.x;
    int nv = E >> 2;
    if (i < nv) {
        vint4 d = __builtin_nontemporal_load(((const vint4*)edst) + i);
        atomicAdd(&deg[d[0]], 1);
        atomicAdd(&deg[d[1]], 1);
        atomicAdd(&deg[d[2]], 1);
        atomicAdd(&deg[d[3]], 1);
    }
    if (i == 0) {
        for (int e = nv << 2; e < E; ++e) atomicAdd(&deg[edst[e]], 1);
    }
}

// Per-block exclusive scan over chunks of 1024; emits per-block totals.
__global__ void scan1_kernel(const int* __restrict__ deg, int* __restrict__ off,
                             int* __restrict__ bsum, int n) {
    __shared__ int sdata[256];
    int tid = threadIdx.x;
    int base = blockIdx.x * SCAN_CHUNK + tid * 4;
    int v[4];
    #pragma unroll
    for (int i = 0; i < 4; ++i) v[i] = (base + i < n) ? deg[base + i] : 0;
    int tsum = v[0] + v[1] + v[2] + v[3];
    sdata[tid] = tsum;
    __syncthreads();
    for (int d = 1; d < 256; d <<= 1) {
        int t = (tid >= d) ? sdata[tid - d] : 0;
        __syncthreads();
        sdata[tid] += t;
        __syncthreads();
    }
    int excl = sdata[tid] - tsum;
    if (tid == 255) bsum[blockIdx.x] = sdata[255];
    int run = excl;
    #pragma unroll
    for (int i = 0; i < 4; ++i) {
        if (base + i < n) off[base + i] = run;
        run += v[i];
    }
}

// Single-block 128-thread exclusive scan of the block sums (nb <= 128).
__global__ void scan2_kernel(int* __restrict__ bsum, int nb) {
    __shared__ int s[128];
    int tid = threadIdx.x;
    int v = (tid < nb) ? bsum[tid] : 0;
    s[tid] = v;
    __syncthreads();
    for (int d = 1; d < 128; d <<= 1) {
        int t = (tid >= d) ? s[tid - d] : 0;
        __syncthreads();
        s[tid] += t;
        __syncthreads();
    }
    if (tid < nb) bsum[tid] = s[tid] - v;   // exclusive
}

// Adds block prefix; also seeds cur = off so scatter needs no off gather.
__global__ void scan3_kernel(int* __restrict__ off, int* __restrict__ cur,
                             const int* __restrict__ bsum, int n) {
    int i = blockIdx.x * blockDim.x + threadIdx.x;
    if (i < n) {
        int v = off[i] + bsum[i / SCAN_CHUNK];
        off[i] = v;
        cur[i] = v;
    }
}

// Single-pass scatter. NT vector loads of the edge streams (no L2 allocate);
// one atomic per edge on pre-seeded cur. Write-amp on pairs is structural
// (R7 lesson) -- ranges would only add replicated read traffic.
__global__ void scatter_kernel(const int* __restrict__ esrc, const int* __restrict__ edst,
                               const float* __restrict__ ew, int* __restrict__ cur,
                               int2* __restrict__ pairs, int E) {
    int i = blockIdx.x * blockDim.x + threadIdx.x;
    int nv = E >> 2;
    if (i < nv) {
        vint4 dd = __builtin_nontemporal_load(((const vint4*)edst) + i);
        vint4 ss = __builtin_nontemporal_load(((const vint4*)esrc) + i);
        vfloat4 ww = __builtin_nontemporal_load(((const vfloat4*)ew) + i);
        #pragma unroll
        for (int j = 0; j < 4; ++j) {
            int p = atomicAdd(&cur[dd[j]], 1);
            int2 pr;
            pr.x = ss[j];
            pr.y = __float_as_int(ww[j]);
            pairs[p] = pr;
        }
    }
    if (i == 0) {
        for (int e = nv << 2; e < E; ++e) {
            int p = atomicAdd(&cur[edst[e]], 1);
            int2 pr;
            pr.x = esrc[e];
            pr.y = __float_as_int(ew[e]);
            pairs[p] = pr;
        }
    }
}

// ---------------- SpMM: one wave per node, 16 edges in flight ----------------
// Hex group g (lanes 4g..4g+3) handles edges k = g, g+16, ... Lane gl of a
// group loads row float4s {gl, gl+4, gl+8, gl+12} -> 4 lanes cover the 256 B
// row. pairs for the node are preloaded once (coalesced, one per lane) and
// broadcast in-register via __shfl -- no dependent pairs load in the loop.
// Cross-group reduce via shfl_xor(4,8,16,32); group 0 stores (each store
// instr = lanes 0-3 x 16 B = one exact 64 B line).

__global__ void spmm_csr_kernel(const float* __restrict__ x,
                                const int2* __restrict__ pairs,
                                const int* __restrict__ off,
                                const int* __restrict__ deg,
                                float* __restrict__ y) {
    int gtid = blockIdx.x * blockDim.x + threadIdx.x;
    int node = gtid >> 6;
    int lane = threadIdx.x & 63;
    int g  = lane >> 2;    // hex group 0..15 = edge slot
    int gl = lane & 3;     // lane within group
    if (node >= N_NODES) return;
    int s0 = off[node];
    int n  = deg[node];

    int2 pr0; pr0.x = 0; pr0.y = 0;
    if (lane < n) pr0 = pairs[s0 + lane];        // coalesced, <=512 B/wave

    float4 a0 = make_float4(0.f, 0.f, 0.f, 0.f);
    float4 a1 = a0, a2 = a0, a3 = a0;

    int trips = (n + 15) >> 4;
    for (int t = 0; t < trips; ++t) {
        int k = g + (t << 4);
        int idx = min(k, 63);
        int src = __shfl(pr0.x, idx);            // register broadcast (VALU)
        int wb  = __shfl(pr0.y, idx);
        if (k >= 64 && k < n) {                  // Poisson(12): essentially never
            int2 p2 = pairs[s0 + k];
            src = p2.x; wb = p2.y;
        }
        if (k < n) {
            float w = __int_as_float(wb);
            const float4* row = (const float4*)(x + (size_t)src * DIM);
            float4 v0 = row[gl];
            float4 v1 = row[gl + 4];
            float4 v2 = row[gl + 8];
            float4 v3 = row[gl + 12];
            a0.x += w * v0.x; a0.y += w * v0.y; a0.z += w * v0.z; a0.w += w * v0.w;
            a1.x += w * v1.x; a1.y += w * v1.y; a1.z += w * v1.z; a1.w += w * v1.w;
            a2.x += w * v2.x; a2.y += w * v2.y; a2.z += w * v2.z; a2.w += w * v2.w;
            a3.x += w * v3.x; a3.y += w * v3.y; a3.z += w * v3.z; a3.w += w * v3.w;
        }
    }
    #pragma unroll
    for (int d = 4; d <= 32; d <<= 1) {
        a0.x += __shfl_xor(a0.x, d); a0.y += __shfl_xor(a0.y, d);
        a0.z += __shfl_xor(a0.z, d); a0.w += __shfl_xor(a0.w, d);
        a1.x += __shfl_xor(a1.x, d); a1.y += __shfl_xor(a1.y, d);
        a1.z += __shfl_xor(a1.z, d); a1.w += __shfl_xor(a1.w, d);
        a2.x += __shfl_xor(a2.x, d); a2.y += __shfl_xor(a2.y, d);
        a2.z += __shfl_xor(a2.z, d); a2.w += __shfl_xor(a2.w, d);
        a3.x += __shfl_xor(a3.x, d); a3.y += __shfl_xor(a3.y, d);
        a3.z += __shfl_xor(a3.z, d); a3.w += __shfl_xor(a3.w, d);
    }
    if (g == 0) {
        vfloat4* yrow = (vfloat4*)(y + (size_t)node * DIM);
        vfloat4 r0 = { a0.x, a0.y, a0.z, a0.w };
        vfloat4 r1 = { a1.x, a1.y, a1.z, a1.w };
        vfloat4 r2 = { a2.x, a2.y, a2.z, a2.w };
        vfloat4 r3 = { a3.x, a3.y, a3.z, a3.w };
        __builtin_nontemporal_store(r0, yrow + gl);        // 4 lanes = 64 B line
        __builtin_nontemporal_store(r1, yrow + gl + 4);
        __builtin_nontemporal_store(r2, yrow + gl + 8);
        __builtin_nontemporal_store(r3, yrow + gl + 12);
    }
}

// ---------------- fallback (atomic path, if ws too small) ----------------

__global__ void spmm_atomic_kernel(const float* __restrict__ x, const float* __restrict__ ew,
                                   const int* __restrict__ esrc, const int* __restrict__ edst,
                                   float* __restrict__ y, int n_edges) {
    long long tid = (long long)blockIdx.x * blockDim.x + threadIdx.x;
    int e = (int)(tid >> 6);
    int d = (int)(tid & 63);
    if (e >= n_edges) return;
    int s = esrc[e]; int t = edst[e]; float w = ew[e];
    atomicAdd(&y[(long long)t * DIM + d], w * x[(long long)s * DIM + d]);
}

extern "C" void kernel_launch(void* const* d_in, const int* in_sizes, int n_in,
                              void* d_out, int out_size, void* d_ws, size_t ws_size,
                              hipStream_t stream) {
    const float* emb  = (const float*)d_in[0];
    const float* ew   = (const float*)d_in[1];
    const int*   esrc = (const int*)d_in[2];
    const int*   edst = (const int*)d_in[3];
    float* out = (float*)d_out;

    const int E = in_sizes[1];
    const size_t layer_elems = (size_t)N_NODES * DIM;

    size_t need = (size_t)E * 8 + (size_t)3 * N_NODES * 4 + 1024;
    hipMemcpyAsync(out, emb, layer_elems * sizeof(float), hipMemcpyDeviceToDevice, stream);

    if (ws_size >= need) {
        char* w = (char*)d_ws;
        int2* pairs = (int2*)w;
        int* deg    = (int*)(w + (size_t)E * 8);
        int* cur    = deg + N_NODES;
        int* off    = cur + N_NODES;
        int* bsum   = off + N_NODES;     // 128 ints

        hipMemsetAsync(deg, 0, (size_t)N_NODES * 4, stream);

        const int nv4 = E >> 2;
        const int vb = (nv4 + 255) / 256;
        hist_kernel<<<vb, 256, 0, stream>>>(edst, deg, E);

        const int nscan = (N_NODES + SCAN_CHUNK - 1) / SCAN_CHUNK;   // 98
        scan1_kernel<<<nscan, 256, 0, stream>>>(deg, off, bsum, N_NODES);
        scan2_kernel<<<1, 128, 0, stream>>>(bsum, nscan);
        scan3_kernel<<<(N_NODES + 255) / 256, 256, 0, stream>>>(off, cur, bsum, N_NODES);

        scatter_kernel<<<vb, 256, 0, stream>>>(esrc, edst, ew, cur, pairs, E);

        const int nb = (N_NODES + 3) / 4;   // 4 waves (nodes) per 256-thread block
        for (int l = 1; l <= 3; ++l) {
            spmm_csr_kernel<<<nb, 256, 0, stream>>>(
                out + (size_t)(l - 1) * layer_elems, pairs, off, deg,
                out + (size_t)l * layer_elems);
        }
    } else {
        hipMemsetAsync(out + layer_elems, 0, 3 * layer_elems * sizeof(float), stream);
        const long long total_threads = (long long)E * 64;
        const int blocks = (int)((total_threads + 255) / 256);
        for (int l = 1; l <= 3; ++l) {
            spmm_atomic_kernel<<<blocks, 256, 0, stream>>>(
                out + (size_t)(l - 1) * layer_elems, ew, esrc, edst,
                out + (size_t)l * layer_elems, E);
        }
    }
}

// Round 7
// 366.349 us; speedup vs baseline: 1.3171x; 1.3171x over previous
//
#include <hip/hip_runtime.h>
#include <hip/hip_fp16.h>

// LightGCN 3-layer propagation. out layout: [4, N_NODES, DIM] f32.
//   layer 0 = embeddings (copy); layer l = SpMM(layer l-1).
//
// Ledger:
//  R4: node-scatter + dst-ranges: WRITE 77.5->73 MB. dur 66.
//  R5: bucket streams: 755us. >700 returning atomics/addr serialize at the
//      coherence point (~410ns). Rule: per-addr atomic multiplicity <= tens.
//  R6: ranges + NT edge loads: WRITE 54.6 MB, dur 64. BEST scatter. Total 393.
//  R7: physical-XCD binding: WRITE unchanged -> %8 heuristic already right;
//      remaining amp structural. Ticket loop added imbalance.
//  R8: no-ranges scatter regressed (WRITE 77.8, dur 100) -> ranges+NT ARE the
//      merge mechanism; restore. Hex spmm (16 chains) slower than oct (8) ->
//      spmm is gather-THROUGHPUT-bound, not latency-bound.
//  R9: fp16-mirror spmm (gather 128 B rows, f32 accum, exact f32 out NT).
//      Infra failure (container died before running) -> R10 resubmits R9
//      unchanged modulo an E>=4 guard.

#define N_NODES 100000
#define DIM 64
#define SCAN_CHUNK 1024

#define NR 8                              // dst ranges (XCD round-robin)
#define RSIZE ((N_NODES + NR - 1) / NR)   // 12500 nodes per range
#define SLICES 128                        // edge slices per range

typedef int   vint4   __attribute__((ext_vector_type(4)));
typedef float vfloat4 __attribute__((ext_vector_type(4)));

union HU { unsigned u; __half2 h; };

// ---------------- layer 0: copy f32 + build fp16 mirror ----------------
__global__ void convert_kernel(const float* __restrict__ emb, float* __restrict__ out0,
                               unsigned short* __restrict__ xh0, int n8) {
    int i = blockIdx.x * blockDim.x + threadIdx.x;   // 8 floats per thread
    if (i >= n8) return;
    const vfloat4* e4 = (const vfloat4*)emb;
    vfloat4 a = __builtin_nontemporal_load(e4 + 2 * i);
    vfloat4 b = __builtin_nontemporal_load(e4 + 2 * i + 1);
    vfloat4* o4 = (vfloat4*)out0;
    __builtin_nontemporal_store(a, o4 + 2 * i);
    __builtin_nontemporal_store(b, o4 + 2 * i + 1);
    HU c0, c1, c2, c3;
    c0.h = __float22half2_rn(make_float2(a[0], a[1]));
    c1.h = __float22half2_rn(make_float2(a[2], a[3]));
    c2.h = __float22half2_rn(make_float2(b[0], b[1]));
    c3.h = __float22half2_rn(make_float2(b[2], b[3]));
    vint4 p = { (int)c0.u, (int)c1.u, (int)c2.u, (int)c3.u };
    ((vint4*)xh0)[i] = p;
}

// ---------------- CSR build ----------------

// Single-pass vectorized histogram (R7 lesson: atomics resolve memory-side,
// issuing XCD irrelevant -> no range replication). ~12/addr: uncontended.
__global__ void hist_kernel(const int* __restrict__ edst, int* __restrict__ deg, int E) {
    int i = blockIdx.x * blockDim.x + threadIdx.x;
    int nv = E >> 2;
    if (i < nv) {
        vint4 d = __builtin_nontemporal_load(((const vint4*)edst) + i);
        atomicAdd(&deg[d[0]], 1);
        atomicAdd(&deg[d[1]], 1);
        atomicAdd(&deg[d[2]], 1);
        atomicAdd(&deg[d[3]], 1);
    }
    if (i == 0) {
        for (int e = nv << 2; e < E; ++e) atomicAdd(&deg[edst[e]], 1);
    }
}

__global__ void scan1_kernel(const int* __restrict__ deg, int* __restrict__ off,
                             int* __restrict__ bsum, int n) {
    __shared__ int sdata[256];
    int tid = threadIdx.x;
    int base = blockIdx.x * SCAN_CHUNK + tid * 4;
    int v[4];
    #pragma unroll
    for (int i = 0; i < 4; ++i) v[i] = (base + i < n) ? deg[base + i] : 0;
    int tsum = v[0] + v[1] + v[2] + v[3];
    sdata[tid] = tsum;
    __syncthreads();
    for (int d = 1; d < 256; d <<= 1) {
        int t = (tid >= d) ? sdata[tid - d] : 0;
        __syncthreads();
        sdata[tid] += t;
        __syncthreads();
    }
    int excl = sdata[tid] - tsum;
    if (tid == 255) bsum[blockIdx.x] = sdata[255];
    int run = excl;
    #pragma unroll
    for (int i = 0; i < 4; ++i) {
        if (base + i < n) off[base + i] = run;
        run += v[i];
    }
}

__global__ void scan2_kernel(int* __restrict__ bsum, int nb) {
    __shared__ int s[128];
    int tid = threadIdx.x;
    int v = (tid < nb) ? bsum[tid] : 0;
    s[tid] = v;
    __syncthreads();
    for (int d = 1; d < 128; d <<= 1) {
        int t = (tid >= d) ? s[tid - d] : 0;
        __syncthreads();
        s[tid] += t;
        __syncthreads();
    }
    if (tid < nb) bsum[tid] = s[tid] - v;   // exclusive
}

// Adds block prefix; seeds cur = off so scatter needs no off gather.
__global__ void scan3_kernel(int* __restrict__ off, int* __restrict__ cur,
                             const int* __restrict__ bsum, int n) {
    int i = blockIdx.x * blockDim.x + threadIdx.x;
    if (i < n) {
        int v = off[i] + bsum[i / SCAN_CHUNK];
        off[i] = v;
        cur[i] = v;
    }
}

// R6-proven scatter: dst-range partitioned (blockIdx%8) + NT edge streams.
// WRITE 54.6 MB / 64us measured. cur pre-seeded with off.
__global__ void scatter_range_kernel(const int* __restrict__ esrc, const int* __restrict__ edst,
                                     const float* __restrict__ ew, int* __restrict__ cur,
                                     int2* __restrict__ pairs, int E, int chunk) {
    const int r = blockIdx.x & (NR - 1);
    const int s = blockIdx.x / NR;
    const int lo = r * RSIZE;
    const int hi = min(lo + RSIZE, N_NODES);
    const int e0 = s * chunk;
    if (e0 >= E) return;
    const int e1 = min(e0 + chunk, E);
    const int nv = (e1 - e0) >> 2;
    const vint4*   s4 = (const vint4*)(esrc + e0);
    const vint4*   d4 = (const vint4*)(edst + e0);
    const vfloat4* w4 = (const vfloat4*)(ew + e0);
    for (int i = threadIdx.x; i < nv; i += blockDim.x) {
        vint4 dd = __builtin_nontemporal_load(d4 + i);
        vint4 ss = __builtin_nontemporal_load(s4 + i);
        vfloat4 ww = __builtin_nontemporal_load(w4 + i);
        #pragma unroll
        for (int j = 0; j < 4; ++j) {
            int dj = dd[j];
            if (dj >= lo && dj < hi) {
                int p = atomicAdd(&cur[dj], 1);
                int2 pr;
                pr.x = ss[j];
                pr.y = __float_as_int(ww[j]);
                pairs[p] = pr;
            }
        }
    }
    for (int e = e0 + (nv << 2) + threadIdx.x; e < e1; e += blockDim.x) {
        int dj = edst[e];
        if (dj >= lo && dj < hi) {
            int p = atomicAdd(&cur[dj], 1);
            int2 pr;
            pr.x = esrc[e];
            pr.y = __float_as_int(ew[e]);
            pairs[p] = pr;
        }
    }
}

// ---------------- SpMM fp16-gather: one wave per node, oct scheme ----------
// Oct o (lanes 8o..8o+7) handles edges k = o, o+8, ... Lane ol loads ONE
// vint4 = 16 B = 8 halves -> 8 lanes cover the full 128 B fp16 row.
// Accumulate f32; cross-oct shfl_xor reduce; oct 0 stores exact f32 row (NT,
// never re-read) + fp16 row into the next layer's mirror (plain store).

__global__ void spmm_h_kernel(const unsigned short* __restrict__ xh,
                              const int2* __restrict__ pairs,
                              const int* __restrict__ off,
                              const int* __restrict__ deg,
                              float* __restrict__ y,
                              unsigned short* __restrict__ yh) {
    int gtid = blockIdx.x * blockDim.x + threadIdx.x;
    int node = gtid >> 6;
    int lane = threadIdx.x & 63;
    int o  = lane >> 3;
    int ol = lane & 7;
    if (node >= N_NODES) return;
    int s0 = off[node];
    int n  = deg[node];
    float a0 = 0.f, a1 = 0.f, a2 = 0.f, a3 = 0.f;
    float a4 = 0.f, a5 = 0.f, a6 = 0.f, a7 = 0.f;   // dims [8ol, 8ol+8)
    for (int k = o; k < n; k += 8) {
        int2 pr = pairs[s0 + k];                     // uniform within oct
        float w = __int_as_float(pr.y);
        const vint4* row = (const vint4*)(xh + (size_t)pr.x * DIM);
        vint4 v = row[ol];                           // 8 lanes x 16 B = 128 B row
        HU c; float2 f;
        c.u = (unsigned)v[0]; f = __half22float2(c.h); a0 += w * f.x; a1 += w * f.y;
        c.u = (unsigned)v[1]; f = __half22float2(c.h); a2 += w * f.x; a3 += w * f.y;
        c.u = (unsigned)v[2]; f = __half22float2(c.h); a4 += w * f.x; a5 += w * f.y;
        c.u = (unsigned)v[3]; f = __half22float2(c.h); a6 += w * f.x; a7 += w * f.y;
    }
    #pragma unroll
    for (int d = 8; d <= 32; d <<= 1) {
        a0 += __shfl_xor(a0, d); a1 += __shfl_xor(a1, d);
        a2 += __shfl_xor(a2, d); a3 += __shfl_xor(a3, d);
        a4 += __shfl_xor(a4, d); a5 += __shfl_xor(a5, d);
        a6 += __shfl_xor(a6, d); a7 += __shfl_xor(a7, d);
    }
    if (o == 0) {
        float* yr = y + (size_t)node * DIM + ol * 8;
        vfloat4 r0 = { a0, a1, a2, a3 };
        vfloat4 r1 = { a4, a5, a6, a7 };
        __builtin_nontemporal_store(r0, (vfloat4*)yr);
        __builtin_nontemporal_store(r1, (vfloat4*)yr + 1);
        HU c0, c1, c2, c3;
        c0.h = __float22half2_rn(make_float2(a0, a1));
        c1.h = __float22half2_rn(make_float2(a2, a3));
        c2.h = __float22half2_rn(make_float2(a4, a5));
        c3.h = __float22half2_rn(make_float2(a6, a7));
        vint4 p = { (int)c0.u, (int)c1.u, (int)c2.u, (int)c3.u };
        *((vint4*)(yh + (size_t)node * DIM + ol * 8)) = p;
    }
}

// ---------------- f32 oct spmm (mid fallback, R6-proven) ----------------

__global__ void spmm_csr_kernel(const float* __restrict__ x,
                                const int2* __restrict__ pairs,
                                const int* __restrict__ off,
                                const int* __restrict__ deg,
                                float* __restrict__ y) {
    int gtid = blockIdx.x * blockDim.x + threadIdx.x;
    int node = gtid >> 6;
    int lane = threadIdx.x & 63;
    int o  = lane >> 3;
    int ol = lane & 7;
    if (node >= N_NODES) return;
    int s0 = off[node];
    int n  = deg[node];
    float4 a0 = make_float4(0.f, 0.f, 0.f, 0.f);
    float4 a1 = a0;
    for (int k = o; k < n; k += 8) {
        int2 pr = pairs[s0 + k];
        float w = __int_as_float(pr.y);
        const float4* row = (const float4*)(x + (size_t)pr.x * DIM);
        float4 v0 = row[ol];
        float4 v1 = row[ol + 8];
        a0.x += w * v0.x; a0.y += w * v0.y; a0.z += w * v0.z; a0.w += w * v0.w;
        a1.x += w * v1.x; a1.y += w * v1.y; a1.z += w * v1.z; a1.w += w * v1.w;
    }
    #pragma unroll
    for (int d = 8; d <= 32; d <<= 1) {
        a0.x += __shfl_xor(a0.x, d); a0.y += __shfl_xor(a0.y, d);
        a0.z += __shfl_xor(a0.z, d); a0.w += __shfl_xor(a0.w, d);
        a1.x += __shfl_xor(a1.x, d); a1.y += __shfl_xor(a1.y, d);
        a1.z += __shfl_xor(a1.z, d); a1.w += __shfl_xor(a1.w, d);
    }
    if (o == 0) {
        vfloat4* yrow = (vfloat4*)(y + (size_t)node * DIM);
        vfloat4 r0 = { a0.x, a0.y, a0.z, a0.w };
        vfloat4 r1 = { a1.x, a1.y, a1.z, a1.w };
        __builtin_nontemporal_store(r0, yrow + ol);
        __builtin_nontemporal_store(r1, yrow + ol + 8);
    }
}

// ---------------- atomic fallback ----------------

__global__ void spmm_atomic_kernel(const float* __restrict__ x, const float* __restrict__ ew,
                                   const int* __restrict__ esrc, const int* __restrict__ edst,
                                   float* __restrict__ y, int n_edges) {
    long long tid = (long long)blockIdx.x * blockDim.x + threadIdx.x;
    int e = (int)(tid >> 6);
    int d = (int)(tid & 63);
    if (e >= n_edges) return;
    int s = esrc[e]; int t = edst[e]; float w = ew[e];
    atomicAdd(&y[(long long)t * DIM + d], w * x[(long long)s * DIM + d]);
}

extern "C" void kernel_launch(void* const* d_in, const int* in_sizes, int n_in,
                              void* d_out, int out_size, void* d_ws, size_t ws_size,
                              hipStream_t stream) {
    const float* emb  = (const float*)d_in[0];
    const float* ew   = (const float*)d_in[1];
    const int*   esrc = (const int*)d_in[2];
    const int*   edst = (const int*)d_in[3];
    float* out = (float*)d_out;

    const int E = in_sizes[1];
    const size_t layer_elems = (size_t)N_NODES * DIM;

    const size_t need_h   = (size_t)E * 8 + 2 * layer_elems * 2 + (size_t)3 * N_NODES * 4 + 1024;
    const size_t need_f32 = (size_t)E * 8 + (size_t)3 * N_NODES * 4 + 1024;

    if (ws_size >= need_h && E >= 4) {
        char* w = (char*)d_ws;
        int2* pairs = (int2*)w;
        unsigned short* xh0 = (unsigned short*)(w + (size_t)E * 8);
        unsigned short* xh1 = xh0 + layer_elems;
        int* deg  = (int*)(xh1 + layer_elems);
        int* cur  = deg + N_NODES;
        int* off  = cur + N_NODES;
        int* bsum = off + N_NODES;     // 128 ints

        hipMemsetAsync(deg, 0, (size_t)N_NODES * 4, stream);

        const int n8 = (int)(layer_elems / 8);
        convert_kernel<<<(n8 + 255) / 256, 256, 0, stream>>>(emb, out, xh0, n8);

        const int nv4 = E >> 2;
        hist_kernel<<<(nv4 + 255) / 256, 256, 0, stream>>>(edst, deg, E);

        const int nscan = (N_NODES + SCAN_CHUNK - 1) / SCAN_CHUNK;   // 98
        scan1_kernel<<<nscan, 256, 0, stream>>>(deg, off, bsum, N_NODES);
        scan2_kernel<<<1, 128, 0, stream>>>(bsum, nscan);
        scan3_kernel<<<(N_NODES + 255) / 256, 256, 0, stream>>>(off, cur, bsum, N_NODES);

        const int chunk = (((E + SLICES - 1) / SLICES) + 3) & ~3;
        scatter_range_kernel<<<NR * SLICES, 256, 0, stream>>>(esrc, edst, ew, cur, pairs, E, chunk);

        const int nb = (N_NODES + 3) / 4;   // 4 waves (nodes) per 256-thread block
        unsigned short* xs[2] = { xh0, xh1 };
        for (int l = 1; l <= 3; ++l) {
            spmm_h_kernel<<<nb, 256, 0, stream>>>(
                xs[(l - 1) & 1], pairs, off, deg,
                out + (size_t)l * layer_elems, xs[l & 1]);
        }
    } else if (ws_size >= need_f32 && E >= 4) {
        char* w = (char*)d_ws;
        int2* pairs = (int2*)w;
        int* deg  = (int*)(w + (size_t)E * 8);
        int* cur  = deg + N_NODES;
        int* off  = cur + N_NODES;
        int* bsum = off + N_NODES;

        hipMemcpyAsync(out, emb, layer_elems * sizeof(float), hipMemcpyDeviceToDevice, stream);
        hipMemsetAsync(deg, 0, (size_t)N_NODES * 4, stream);

        const int nv4 = E >> 2;
        hist_kernel<<<(nv4 + 255) / 256, 256, 0, stream>>>(edst, deg, E);

        const int nscan = (N_NODES + SCAN_CHUNK - 1) / SCAN_CHUNK;
        scan1_kernel<<<nscan, 256, 0, stream>>>(deg, off, bsum, N_NODES);
        scan2_kernel<<<1, 128, 0, stream>>>(bsum, nscan);
        scan3_kernel<<<(N_NODES + 255) / 256, 256, 0, stream>>>(off, cur, bsum, N_NODES);

        const int chunk = (((E + SLICES - 1) / SLICES) + 3) & ~3;
        scatter_range_kernel<<<NR * SLICES, 256, 0, stream>>>(esrc, edst, ew, cur, pairs, E, chunk);

        const int nb = (N_NODES + 3) / 4;
        for (int l = 1; l <= 3; ++l) {
            spmm_csr_kernel<<<nb, 256, 0, stream>>>(
                out + (size_t)(l - 1) * layer_elems, pairs, off, deg,
                out + (size_t)l * layer_elems);
        }
    } else {
        hipMemcpyAsync(out, emb, layer_elems * sizeof(float), hipMemcpyDeviceToDevice, stream);
        hipMemsetAsync(out + layer_elems, 0, 3 * layer_elems * sizeof(float), stream);
        const long long total_threads = (long long)E * 64;
        const int blocks = (int)((total_threads + 255) / 256);
        for (int l = 1; l <= 3; ++l) {
            spmm_atomic_kernel<<<blocks, 256, 0, stream>>>(
                out + (size_t)(l - 1) * layer_elems, ew, esrc, edst,
                out + (size_t)l * layer_elems, E);
        }
    }
}